// Round 10
// baseline (286.581 us; speedup 1.0000x reference)
//
#include <hip/hip_runtime.h>
#include <stdint.h>

// Problem constants
#define NLAYERS 32
#define DSIZE   1024
#define OSIZE   1024
#define BATCH   32
#define SEQ     256

// ws layout (ints): [0]=ntiles; [16..272)=perm; [512 + 4*t ..]=tile{layer, rank_base, nranks, pad}
#define WS_PERM  16
#define WS_TILE  512
#define MAX_TILES 88   // sum ceil(cnt/4) <= 64 + 24 = 88
#define NSPLIT   16    // o-dim tiles of 64

#define BK   32
#define NIT  (DSIZE / BK)   // 32
#define THREADS 512

typedef __attribute__((ext_vector_type(8)))  short short8;
typedef __attribute__((ext_vector_type(16))) float f32x16;

__global__ void prep_kernel(const int* __restrict__ layer_idx, int* __restrict__ wsi) {
    __shared__ int cnt[NLAYERS];
    __shared__ int start_[NLAYERS];
    __shared__ int cursor[NLAYERS];
    const int t = threadIdx.x;
    if (t < NLAYERS) cnt[t] = 0;
    __syncthreads();
    int l = 0;
    if (t < SEQ) { l = layer_idx[t]; atomicAdd(&cnt[l], 1); }
    __syncthreads();
    if (t == 0) {
        int acc = 0;
        for (int i = 0; i < NLAYERS; ++i) { start_[i] = acc; cursor[i] = acc; acc += cnt[i]; }
    }
    __syncthreads();
    if (t < SEQ) {
        int r = atomicAdd(&cursor[l], 1);
        wsi[WS_PERM + r] = t;           // perm[rank] = s
    }
    if (t == 0) {
        int nt = 0;
        for (int i = 0; i < NLAYERS; ++i) {
            const int c = cnt[i];
            for (int j = 0; j < c; j += 4) {
                wsi[WS_TILE + nt*4 + 0] = i;
                wsi[WS_TILE + nt*4 + 1] = start_[i] + j;
                wsi[WS_TILE + nt*4 + 2] = (c - j < 4) ? (c - j) : 4;
                ++nt;
            }
        }
        wsi[0] = nt;   // 64..88
    }
}

// round-to-nearest fp32->bf16 pair pack: low16 = bf16(a), high16 = bf16(b)
static __device__ __forceinline__ unsigned pk2(float a, float b) {
    unsigned ua = __builtin_bit_cast(unsigned, a) + 0x8000u;
    unsigned ub = __builtin_bit_cast(unsigned, b) + 0x8000u;
    return __builtin_amdgcn_perm(ub, ua, 0x07060302u);  // {ua[2],ua[3],ub[2],ub[3]}
}

// Direct HBM->LDS DMA, 16B per lane. LDS dest = wave-uniform base + lane*16
// (linear); global src is per-lane (carries the inverse swizzle).
static __device__ __forceinline__ void gload16(const float* g, float* l) {
    __builtin_amdgcn_global_load_lds(
        (const __attribute__((address_space(1))) void*)g,
        (__attribute__((address_space(3))) void*)l, 16, 0, 0);
}

// Tile: 128 m-rows (4 ranks x 32 batch) x 64 o-cols, BK=32 (fp32 in LDS), 8 waves.
// Wave wv: rank ro=wv>>1, n-half nh=wv&1 -> one 32x32 acc (16 AGPR).
// LDS: A[2][128][32]f32 (2x16KB) + B[2][64][32]f32 (2x8KB) = 48KB -> 3 blocks/CU
// = 24 waves/CU.
// Staging via global_load_lds (no VGPR round-trip): per wave per iter 3 DMA
// instrs (A rows [wv*16,+16) as 2x1KB, B rows [wv*8,+8) as 1KB).
// Swizzle (rule: linear dest + inverse-swz source + swz read): LDS row r,
// 16B-slot s holds global granule s^(r&7). DMA lane l writes row base+(l>>3),
// slot l&7 -> reads global granule (l&7)^(l>>3). Fragment read of granule g
// at slot g^(row&7): enumerated 8 cyc/wave ds_read (conflict-free minimum).
// K-loop (T4 counted-vmcnt): issue 3 DMA into buf^1 -> s_waitcnt vmcnt(3)
// (waits ONLY previous tile's DMAs; new 3 stay in flight through compute)
// -> barrier -> 8 ds_read + 16 pk2 + 2 MFMA -> lgkmcnt(0) barrier.
// Grid 1408. XCD run-partition (R6: FETCH ~compulsory ~101MB) kept verbatim.
__global__ __launch_bounds__(THREADS, 6) void gemm_kernel(
        const float* __restrict__ x, const float* __restrict__ wgt,
        const int* __restrict__ wsi, float* __restrict__ out) {
    const int ntiles = wsi[0];
    const int xcd = blockIdx.x & 7;
    const int idx = blockIdx.x >> 3;                    // 0..175
    const int g_lo = (xcd * ntiles) >> 3;
    const int g_hi = ((xcd + 1) * ntiles) >> 3;
    const int nblk = (g_hi - g_lo) << 4;                // chunks-in-run * 16 ntiles
    if (idx >= nblk) return;
    const int mt    = g_lo + (idx >> 4);                // chunk id
    const int ntile = idx & 15;                         // o block of 64
    const int layer     = wsi[WS_TILE + mt*4 + 0];
    const int rank_base = wsi[WS_TILE + mt*4 + 1];
    const int nranks    = wsi[WS_TILE + mt*4 + 2];

    __shared__ __align__(16) float ldsA[2][128 * BK];   // 32 KB
    __shared__ __align__(16) float ldsB[2][64 * BK];    // 16 KB

    const int t    = threadIdx.x;
    const int lane = t & 63;
    const int wv   = t >> 6;          // 0..7
    const int l31  = lane & 31;
    const int lh   = lane >> 5;

    // ---- staging mapping (per wave): A rows [wv*16, wv*16+16), B rows [wv*8, +8)
    // lane l: row_off = l>>3, slot = l&7; inverse-swz source col = 4*((l&7)^(l>>3))
    const int swzf = ((lane & 7) ^ (lane >> 3)) << 2;   // floats

    const int riA = wv >> 1;                            // rank for this wave's A rows
    const int sW  = (riA < nranks) ? wsi[WS_PERM + rank_base + riA] : 0;
    const int b0  = ((wv & 1) << 4) + (lane >> 3);      // batch for A-instr 0 (rows wv*16+0..7)
    const float* aptr0 = x + (((size_t)(b0 * SEQ + sW)) << 10) + swzf;
    const float* aptr1 = aptr0 + ((size_t)8 * SEQ << 10);          // batch +8 (rows +8)
    const int rB0 = ntile * 64 + wv * 8 + (lane >> 3);  // B global o-row
    const float* bptr = wgt + ((size_t)layer << 20) + (((size_t)rB0) << 10) + swzf;

    float* dA = &ldsA[0][0] + wv * 16 * BK;             // wave-uniform LDS dest bases
    float* dB = &ldsB[0][0] + wv * 8 * BK;

    // ---- compute mapping: wave = (rank ro, n-half nh), 32x32 output
    const int ro  = wv >> 1;
    const int nh  = wv & 1;
    const int rsw = l31 & 7;                            // read-side swizzle (row&7)
    const int oA  = (ro * 32 + l31) * BK;               // A row base (floats)
    const int oB  = (nh * 32 + l31) * BK;               // B row base (floats)

    f32x16 acc;
    #pragma unroll
    for (int r = 0; r < 16; ++r) acc[r] = 0.f;

    // prologue: DMA tile 0 into buf 0 (no wait here; barrier in first iteration)
    gload16(aptr0, dA);
    gload16(aptr1, dA + 8 * BK);
    gload16(bptr,  dB);

    #pragma unroll 1
    for (int kt = 0; kt < NIT; ++kt) {
        const int c = kt & 1;
        if (kt + 1 < NIT) {
            const int kn = (kt + 1) * BK;
            const int nb = (c ^ 1);
            gload16(aptr0 + kn, dA + nb * 128 * BK);
            gload16(aptr1 + kn, dA + nb * 128 * BK + 8 * BK);
            gload16(bptr  + kn, dB + nb * 64 * BK);
            // wait ONLY the previous tile's 3 DMAs; the 3 just issued stay in flight
            asm volatile("s_waitcnt vmcnt(3)\n\ts_barrier" ::: "memory");
        } else {
            asm volatile("s_waitcnt vmcnt(0)\n\ts_barrier" ::: "memory");
        }
        const float* pa = &ldsA[c][oA];
        const float* pb = &ldsB[c][oB];
        #pragma unroll
        for (int sub = 0; sub < 2; ++sub) {
            const int g0 = 4 * sub + 2 * lh;            // original 16B granule of k-slice
            float4 alo = *(const float4*)&pa[((g0    ) ^ rsw) << 2];
            float4 ahi = *(const float4*)&pa[((g0 + 1) ^ rsw) << 2];
            float4 blo = *(const float4*)&pb[((g0    ) ^ rsw) << 2];
            float4 bhi = *(const float4*)&pb[((g0 + 1) ^ rsw) << 2];
            uint4 ua, ub;
            ua.x = pk2(alo.x, alo.y); ua.y = pk2(alo.z, alo.w);
            ua.z = pk2(ahi.x, ahi.y); ua.w = pk2(ahi.z, ahi.w);
            ub.x = pk2(blo.x, blo.y); ub.y = pk2(blo.z, blo.w);
            ub.z = pk2(bhi.x, bhi.y); ub.w = pk2(bhi.z, bhi.w);
            short8 a0 = __builtin_bit_cast(short8, ua);
            short8 bb = __builtin_bit_cast(short8, ub);
            acc = __builtin_amdgcn_mfma_f32_32x32x16_bf16(a0, bb, acc, 0, 0, 0);
        }
        // reads of buf c done before next iteration's DMA overwrites it
        asm volatile("s_waitcnt lgkmcnt(0)\n\ts_barrier" ::: "memory");
    }

    // epilogue: C/D layout col = lane&31, row = (reg&3) + 8*(reg>>2) + 4*(lane>>5)
    if (ro < nranks) {
        const int s = wsi[WS_PERM + rank_base + ro];
        const int ocol = ntile * 64 + nh * 32 + l31;
        #pragma unroll
        for (int r = 0; r < 16; ++r) {
            const int brow = (r & 3) + 8 * (r >> 2) + 4 * lh;  // = batch b
            out[(((size_t)(brow * SEQ + s)) << 10) + ocol] = acc[r];
        }
    }
}

extern "C" void kernel_launch(void* const* d_in, const int* in_sizes, int n_in,
                              void* d_out, int out_size, void* d_ws, size_t ws_size,
                              hipStream_t stream) {
    const float* x         = (const float*)d_in[0];
    const int*   layer_idx = (const int*)  d_in[1];
    const float* weight    = (const float*)d_in[2];
    float* out = (float*)d_out;
    int*   wsi = (int*)d_ws;

    prep_kernel<<<1, 256, 0, stream>>>(layer_idx, wsi);
    gemm_kernel<<<MAX_TILES * NSPLIT, THREADS, 0, stream>>>(x, weight, wsi, out);
}